// Round 5
// baseline (194.731 us; speedup 1.0000x reference)
//
#include <hip/hip_runtime.h>

#define T_LEN 128
#define NB_BINS 15
#define SEQS_PER_BLOCK 16

// ---------------------------------------------------------------------------
// k1: per-block tile = 16 sequences x all 128 timesteps (256KB contiguous L).
//  - static dots (gs,bs) computed in-block by threads 0..15
//  - 8 lanes per L-row, 1KiB contiguous per wave-instruction, one-ahead
//    prefetch; emits per-step packed float4(a, c, y, m) into an LDS tile
//  - tile flushed t-major to staged[t*N + n] (256B contiguous pieces)
//      a = gA*S + gd + gs            (zpm additive term)
//      c = b0 + bin + bd + bs + bT*t/30   (logit additive term)
// ---------------------------------------------------------------------------
__global__ __launch_bounds__(256) void k_pre(
    const float4* __restrict__ L4,
    const float*  __restrict__ S,
    const float*  __restrict__ Y,
    const float*  __restrict__ M,
    const float4* __restrict__ C4,
    const float4* __restrict__ wgs4,
    const float4* __restrict__ wbs4,
    const float4* __restrict__ wgd4,
    const float4* __restrict__ wbd4,
    const float*  __restrict__ p_gA,
    const float*  __restrict__ p_b0,
    const float*  __restrict__ p_bbins,
    const float*  __restrict__ p_bT,
    float4* __restrict__ staged,
    int Nseq)
{
    __shared__ float4 tile[T_LEN][SEQS_PER_BLOCK + 1];   // +1 pad: bank spread
    __shared__ float sgs[SEQS_PER_BLOCK], sbs[SEQS_PER_BLOCK];
    __shared__ float sbins[NB_BINS];

    const int tid = threadIdx.x;
    if (tid < NB_BINS) sbins[tid] = p_bbins[tid];

    const int n0 = blockIdx.x * SEQS_PER_BLOCK;

    // static dots for this block's 16 sequences
    if (tid < SEQS_PER_BLOCK) {
        float gs = 0.0f, bs = 0.0f;
        #pragma unroll
        for (int i = 0; i < 4; ++i) {
            float4 c  = C4[(n0 + tid) * 4 + i];
            float4 wg = wgs4[i];
            float4 wb = wbs4[i];
            gs += c.x * wg.x + c.y * wg.y + c.z * wg.z + c.w * wg.w;
            bs += c.x * wb.x + c.y * wb.y + c.z * wb.z + c.w * wb.w;
        }
        sgs[tid] = gs; sbs[tid] = bs;
    }
    __syncthreads();

    const float gA   = p_gA[0];
    const float b0   = p_b0[0];
    const float bT30 = p_bT[0] * (1.0f / 30.0f);

    const int lane8 = tid & 7;
    const int gid   = tid >> 3;              // 0..31 row-groups
    const float4 wg = wgd4[lane8];
    const float4 wb = wbd4[lane8];

    const size_t rowbase = (size_t)n0 * T_LEN;

    // 64 iterations x 32 groups = 2048 rows (16 seqs x 128 t), contiguous
    float4 v = L4[(rowbase + gid) * 8 + lane8];
    for (int it = 0; it < 64; ++it) {
        const int    lrow = it * 32 + gid;
        const size_t row  = rowbase + lrow;

        float4 vn = v;
        if (it + 1 < 64) vn = L4[(row + 32) * 8 + lane8];

        float g = v.x * wg.x + v.y * wg.y + v.z * wg.z + v.w * wg.w;
        float b = v.x * wb.x + v.y * wb.y + v.z * wb.z + v.w * wb.w;
        #pragma unroll
        for (int off = 1; off < 8; off <<= 1) {
            g += __shfl_xor(g, off, 64);
            b += __shfl_xor(b, off, 64);
        }

        const int nl = lrow >> 7;            // local seq 0..15
        const int t  = lrow & 127;
        const float s_v = S[row];
        const float y_v = Y[row];
        const float m_v = M[row];
        int cnt = (int)fmaxf(0.0f, fminf(14.0f,
                      ceilf(fmaf(s_v, 3.0f, 7.5f)) - 1.0f));
        const float a = gA * s_v + g + sgs[nl];
        const float c = b0 + sbins[cnt] + b + sbs[nl] + bT30 * (float)t;

        if (lane8 == 0) tile[t][nl] = make_float4(a, c, y_v, m_v);
        v = vn;
    }
    __syncthreads();

    // flush tile t-major: 2048 float4s, 8 per thread; wave covers 4 t x 16 n
    #pragma unroll
    for (int p = 0; p < 8; ++p) {
        const int idx = p * 256 + tid;
        const int t = idx >> 4, j = idx & 15;
        staged[(size_t)t * Nseq + n0 + j] = tile[t][j];
    }
}

// ---------------------------------------------------------------------------
// k2: per-sequence scan, 1 thread/seq, t-major streaming reads.
// At step t the grid reads staged[t*N + ...] in address order (1KiB/wave).
// Triple-buffered 4-step chunks, prefetch distance 2 chunks (8 steps).
// Outputs written n-major as per-chunk float4 (L2 merges lines).
// ---------------------------------------------------------------------------
__global__ __launch_bounds__(64) void k_scan(
    const float4* __restrict__ staged,
    const float*  __restrict__ p_psi,
    const float*  __restrict__ p_lsz,
    const float*  __restrict__ p_bZ,
    float4* __restrict__ Zf4,
    float4* __restrict__ Zv4,
    float*  __restrict__ ll_out,
    int Nseq)
{
    const int n = blockIdx.x * 64 + threadIdx.x;

    const float psi  = p_psi[0];
    const float e    = __expf(p_lsz[0]);
    const float sig2 = e * e;
    const float bZ   = p_bZ[0];
    const float psi2 = psi * psi;
    const float bZ2  = bZ * bZ;

    float zm = 0.0f, zvv = 1.0f, ll = 0.0f;

#define STEP(PK, PMOUT, PVOUT) do {                                       \
        const float zpm = fmaf(psi, zm, PK.x);                            \
        const float zpv = fmaf(psi2, zvv, sig2);                          \
        float logit = fmaf(bZ, zpm, PK.y);                                \
        logit = fminf(fmaxf(logit, -20.0f), 20.0f);                       \
        const float prob = __builtin_amdgcn_rcpf(1.0f + __expf(-logit));  \
        const float grad = (PK.z - prob) * bZ * PK.w;                     \
        const float hess = fmaf(bZ2 * prob * (1.0f - prob), PK.w, 1e-6f); \
        const float pvv  = __builtin_amdgcn_rcpf(                         \
                             __builtin_amdgcn_rcpf(zpv + 1e-8f) + hess);  \
        const float pmm  = fmaf(pvv, grad, zpm);                          \
        ll += (PK.z * __logf(prob + 1e-10f)                               \
             + (1.0f - PK.z) * __logf(1.0f - prob + 1e-10f)) * PK.w;      \
        zm = pmm; zvv = pvv; PMOUT = pmm; PVOUT = pvv;                    \
    } while (0)

#define LOADBUF(B0, B1, B2, B3, CIDX) do {                                \
        const int cc = (CIDX) > 31 ? 31 : (CIDX);                         \
        const float4* p = staged + (size_t)(cc * 4) * Nseq + n;           \
        B0 = p[0];                                                        \
        B1 = p[(size_t)Nseq];                                             \
        B2 = p[2 * (size_t)Nseq];                                         \
        B3 = p[3 * (size_t)Nseq];                                         \
    } while (0)

#define COMP(B0, B1, B2, B3, K) do {                                      \
        float pm0, pm1, pm2, pm3, pv0, pv1, pv2, pv3;                     \
        STEP(B0, pm0, pv0);                                               \
        STEP(B1, pm1, pv1);                                               \
        STEP(B2, pm2, pv2);                                               \
        STEP(B3, pm3, pv3);                                               \
        Zf4[(size_t)n * 32 + (K)] = make_float4(pm0, pm1, pm2, pm3);      \
        Zv4[(size_t)n * 32 + (K)] = make_float4(pv0, pv1, pv2, pv3);      \
    } while (0)

    float4 A0, A1, A2, A3, B0, B1, B2, B3, C0, C1, C2, C3;
    LOADBUF(A0, A1, A2, A3, 0);
    LOADBUF(B0, B1, B2, B3, 1);
    LOADBUF(C0, C1, C2, C3, 2);

    for (int k = 0; k < 30; k += 3) {
        COMP(A0, A1, A2, A3, k);     LOADBUF(A0, A1, A2, A3, k + 3);
        COMP(B0, B1, B2, B3, k + 1); LOADBUF(B0, B1, B2, B3, k + 4);
        COMP(C0, C1, C2, C3, k + 2); LOADBUF(C0, C1, C2, C3, k + 5);
    }
    COMP(A0, A1, A2, A3, 30);
    COMP(B0, B1, B2, B3, 31);
#undef COMP
#undef LOADBUF
#undef STEP

    // full-wave ll reduction, one atomic per wave
    #pragma unroll
    for (int off = 1; off < 64; off <<= 1) ll += __shfl_xor(ll, off, 64);
    if ((threadIdx.x & 63) == 0) atomicAdd(ll_out, ll);
}

// ---------------------------------------------------------------------------
extern "C" void kernel_launch(void* const* d_in, const int* in_sizes, int n_in,
                              void* d_out, int out_size, void* d_ws, size_t ws_size,
                              hipStream_t stream) {
    const float* S     = (const float*)d_in[0];
    const float* L     = (const float*)d_in[1];
    const float* C     = (const float*)d_in[2];
    const float* Y     = (const float*)d_in[3];
    const float* M     = (const float*)d_in[4];
    const float* psi   = (const float*)d_in[5];
    const float* gA    = (const float*)d_in[6];
    const float* wgd   = (const float*)d_in[7];
    const float* wgs   = (const float*)d_in[8];
    const float* lsz   = (const float*)d_in[9];
    const float* b0    = (const float*)d_in[10];
    const float* bZ    = (const float*)d_in[11];
    const float* bbins = (const float*)d_in[12];
    const float* wbd   = (const float*)d_in[13];
    const float* wbs   = (const float*)d_in[14];
    const float* bT    = (const float*)d_in[15];

    const int NT    = in_sizes[0];        // N*T = 4194304
    const int n_seq = NT / T_LEN;         // 32768

    float* zf = (float*)d_out;
    float* zv = zf + NT;
    float* ll = zf + 2 * (size_t)NT;

    float4* staged = (float4*)d_ws;       // NT float4s = 67 MB (ws is ~2GB)

    hipMemsetAsync((void*)ll, 0, sizeof(float), stream);

    // k1: tile-streaming precompute + t-major transpose into d_ws
    k_pre<<<n_seq / SEQS_PER_BLOCK, 256, 0, stream>>>(
        reinterpret_cast<const float4*>(L),
        S, Y, M,
        reinterpret_cast<const float4*>(C),
        reinterpret_cast<const float4*>(wgs),
        reinterpret_cast<const float4*>(wbs),
        reinterpret_cast<const float4*>(wgd),
        reinterpret_cast<const float4*>(wbd),
        gA, b0, bbins, bT,
        staged, n_seq);

    // k2: t-major streaming scan
    k_scan<<<n_seq / 64, 64, 0, stream>>>(
        staged, psi, lsz, bZ,
        reinterpret_cast<float4*>(zf),
        reinterpret_cast<float4*>(zv),
        ll, n_seq);
}

// Round 6
// 193.736 us; speedup vs baseline: 1.0051x; 1.0051x over previous
//
#include <hip/hip_runtime.h>

#define T_LEN 128
#define NB_BINS 15
#define SPB 16            // sequences per block

// ---------------------------------------------------------------------------
// Single fused kernel. Block = 16 sequences.
// Phase 0: static dots (threads 0..15), bins -> LDS.
// Phase 1: stream 256KB contiguous L slab (8 lanes/row, 1KiB/wave-instr,
//          one-ahead prefetch); lane0 of each row-group side-loads s,y,m
//          (8 consecutive floats per wave per array) and writes packed
//          float4(a, c, y, m) into LDS tile (pad 17 -> conflict-free).
//            a = gA*s + gd + gs,  c = b0 + bin + bd + bs + bT*t/30
// Phase 2: threads 0..15 run the 128-step scan from LDS; outputs written
//          directly (only HBM writes of the kernel). ll wave-reduced,
//          one atomic per block.
// ---------------------------------------------------------------------------
__global__ __launch_bounds__(256) void k_all(
    const float*  __restrict__ S,
    const float*  __restrict__ Y,
    const float*  __restrict__ M,
    const float4* __restrict__ L4,
    const float4* __restrict__ C4,
    const float4* __restrict__ wgs4,
    const float4* __restrict__ wbs4,
    const float4* __restrict__ wgd4,
    const float4* __restrict__ wbd4,
    const float*  __restrict__ p_psi,
    const float*  __restrict__ p_gA,
    const float*  __restrict__ p_lsz,
    const float*  __restrict__ p_b0,
    const float*  __restrict__ p_bZ,
    const float*  __restrict__ p_bbins,
    const float*  __restrict__ p_bT,
    float4* __restrict__ Zf4,
    float4* __restrict__ Zv4,
    float*  __restrict__ ll_out)
{
    __shared__ float4 tile[T_LEN][SPB + 1];   // (a,c,y,m); +1 pad: bank spread
    __shared__ float sgs[SPB], sbs[SPB];
    __shared__ float sbins[NB_BINS];

    const int tid = threadIdx.x;
    const int n0  = blockIdx.x * SPB;

    if (tid < NB_BINS) sbins[tid] = p_bbins[tid];
    if (tid < SPB) {
        float gs = 0.0f, bs = 0.0f;
        #pragma unroll
        for (int i = 0; i < 4; ++i) {
            float4 c  = C4[(n0 + tid) * 4 + i];
            float4 wg = wgs4[i];
            float4 wb = wbs4[i];
            gs += c.x * wg.x + c.y * wg.y + c.z * wg.z + c.w * wg.w;
            bs += c.x * wb.x + c.y * wb.y + c.z * wb.z + c.w * wb.w;
        }
        sgs[tid] = gs; sbs[tid] = bs;
    }
    __syncthreads();

    const float gA   = p_gA[0];
    const float b0   = p_b0[0];
    const float bT30 = p_bT[0] * (1.0f / 30.0f);

    const int lane8 = tid & 7;
    const int gid   = tid >> 3;              // 32 row-groups per block
    const float4 wg = wgd4[lane8];
    const float4 wb = wbd4[lane8];
    const size_t rowbase = (size_t)n0 * T_LEN;

    // ---- phase 1: 64 iters x 32 groups = 2048 rows (16 seq x 128 t) ----
    float4 v = L4[(rowbase + gid) * 8 + lane8];
    for (int it = 0; it < 64; ++it) {
        const int    lrow = it * 32 + gid;
        const size_t row  = rowbase + lrow;

        float4 vn = v;
        if (it + 1 < 64) vn = L4[(row + 32) * 8 + lane8];

        // side-loads: 8 active lanes/wave read 8 consecutive floats per array
        float s_v = 0.0f, y_v = 0.0f, m_v = 0.0f;
        if (lane8 == 0) { s_v = S[row]; y_v = Y[row]; m_v = M[row]; }

        float g = v.x * wg.x + v.y * wg.y + v.z * wg.z + v.w * wg.w;
        float b = v.x * wb.x + v.y * wb.y + v.z * wb.z + v.w * wb.w;
        #pragma unroll
        for (int off = 1; off < 8; off <<= 1) {
            g += __shfl_xor(g, off, 64);
            b += __shfl_xor(b, off, 64);
        }

        if (lane8 == 0) {
            const int nl = lrow >> 7;
            const int t  = lrow & 127;
            int cnt = (int)fmaxf(0.0f, fminf(14.0f,
                          ceilf(fmaf(s_v, 3.0f, 7.5f)) - 1.0f));
            const float a = gA * s_v + g + sgs[nl];
            const float c = b0 + sbins[cnt] + b + sbs[nl] + bT30 * (float)t;
            tile[t][nl] = make_float4(a, c, y_v, m_v);
        }
        v = vn;
    }
    __syncthreads();

    // ---- phase 2: 16-thread scan from LDS ----
    float ll = 0.0f;
    if (tid < SPB) {
        const float psi  = p_psi[0];
        const float e    = __expf(p_lsz[0]);
        const float sig2 = e * e;
        const float bZ   = p_bZ[0];
        const float psi2 = psi * psi;
        const float bZ2  = bZ * bZ;

        float zm = 0.0f, zvv = 1.0f;
        const int    nl = tid;
        const size_t ob = (size_t)(n0 + nl) * 32;   // float4 units

        for (int cnk = 0; cnk < 16; ++cnk) {
            float pm[8], pv[8];                      // static-indexed (unroll)
            #pragma unroll
            for (int j = 0; j < 8; ++j) {
                const float4 pk = tile[cnk * 8 + j][nl];
                const float zpm = fmaf(psi, zm, pk.x);
                const float zpv = fmaf(psi2, zvv, sig2);
                float logit = fmaf(bZ, zpm, pk.y);
                logit = fminf(fmaxf(logit, -20.0f), 20.0f);
                const float prob = __builtin_amdgcn_rcpf(1.0f + __expf(-logit));
                const float grad = (pk.z - prob) * bZ * pk.w;
                const float hess = fmaf(bZ2 * prob * (1.0f - prob), pk.w, 1e-6f);
                const float pvv  = __builtin_amdgcn_rcpf(
                                     __builtin_amdgcn_rcpf(zpv + 1e-8f) + hess);
                const float pmm  = fmaf(pvv, grad, zpm);
                ll += (pk.z * __logf(prob + 1e-10f)
                     + (1.0f - pk.z) * __logf(1.0f - prob + 1e-10f)) * pk.w;
                zm = pmm; zvv = pvv; pm[j] = pmm; pv[j] = pvv;
            }
            Zf4[ob + cnk * 2]     = make_float4(pm[0], pm[1], pm[2], pm[3]);
            Zf4[ob + cnk * 2 + 1] = make_float4(pm[4], pm[5], pm[6], pm[7]);
            Zv4[ob + cnk * 2]     = make_float4(pv[0], pv[1], pv[2], pv[3]);
            Zv4[ob + cnk * 2 + 1] = make_float4(pv[4], pv[5], pv[6], pv[7]);
        }
    }

    // wave0 lanes 0..15 hold the block's ll; lanes 16..63 contribute zeros
    #pragma unroll
    for (int off = 1; off < 64; off <<= 1) ll += __shfl_xor(ll, off, 64);
    if (tid == 0) atomicAdd(ll_out, ll);
}

// ---------------------------------------------------------------------------
extern "C" void kernel_launch(void* const* d_in, const int* in_sizes, int n_in,
                              void* d_out, int out_size, void* d_ws, size_t ws_size,
                              hipStream_t stream) {
    const float* S     = (const float*)d_in[0];
    const float* L     = (const float*)d_in[1];
    const float* C     = (const float*)d_in[2];
    const float* Y     = (const float*)d_in[3];
    const float* M     = (const float*)d_in[4];
    const float* psi   = (const float*)d_in[5];
    const float* gA    = (const float*)d_in[6];
    const float* wgd   = (const float*)d_in[7];
    const float* wgs   = (const float*)d_in[8];
    const float* lsz   = (const float*)d_in[9];
    const float* b0    = (const float*)d_in[10];
    const float* bZ    = (const float*)d_in[11];
    const float* bbins = (const float*)d_in[12];
    const float* wbd   = (const float*)d_in[13];
    const float* wbs   = (const float*)d_in[14];
    const float* bT    = (const float*)d_in[15];

    const int NT    = in_sizes[0];        // N*T = 4194304
    const int n_seq = NT / T_LEN;         // 32768

    float* zf = (float*)d_out;
    float* zv = zf + NT;
    float* ll = zf + 2 * (size_t)NT;

    hipMemsetAsync((void*)ll, 0, sizeof(float), stream);

    k_all<<<n_seq / SPB, 256, 0, stream>>>(
        S, Y, M,
        reinterpret_cast<const float4*>(L),
        reinterpret_cast<const float4*>(C),
        reinterpret_cast<const float4*>(wgs),
        reinterpret_cast<const float4*>(wbs),
        reinterpret_cast<const float4*>(wgd),
        reinterpret_cast<const float4*>(wbd),
        psi, gA, lsz, b0, bZ, bbins, bT,
        reinterpret_cast<float4*>(zf),
        reinterpret_cast<float4*>(zv),
        ll);
}